// Round 6
// baseline (51784.131 us; speedup 1.0000x reference)
//
#include <hip/hip_runtime.h>
#include <math.h>

#define T_   1024
#define B_   128
#define H_   512
#define I_   256
#define NWG  192     // 3 gates x 64 col-groups
#define NTH  1024    // 16 waves/CU -> 4 waves/SIMD (TLP hides MALL latency)
#define NC   8       // columns per workgroup
#define NKQ  8       // k-slices per wg (tid>>7)

// ---- coherent (cross-XCD) accesses: per-access, NO cache-wide fences, NO RMW ----
__device__ __forceinline__ float co_ld(const float* p) {
    return __hip_atomic_load(p, __ATOMIC_RELAXED, __HIP_MEMORY_SCOPE_AGENT);
}
__device__ __forceinline__ void co_st(float* p, float v) {
    __hip_atomic_store(p, v, __ATOMIC_RELAXED, __HIP_MEMORY_SCOPE_AGENT);
}
__device__ __forceinline__ int co_ldi(const int* p) {
    return __hip_atomic_load(p, __ATOMIC_RELAXED, __HIP_MEMORY_SCOPE_AGENT);
}
__device__ __forceinline__ void co_sti(int* p, int v) {
    __hip_atomic_store(p, v, __ATOMIC_RELAXED, __HIP_MEMORY_SCOPE_AGENT);
}

// publish: __syncthreads() drains vmcnt (sc1 data stores reach the coherence
// point), then leader writes this wg's OWN slot (plain store, no RMW).
__device__ __forceinline__ void publish(int* slot, int v) {
    __syncthreads();
    if (threadIdx.x == 0) co_sti(slot, v);
}

// h-side GEMM slice: 64 k-values, depth-8 double-buffered coherent loads.
// AT points at exchange buffer column base + r; wlds at [k0][0] of this wg's
// weight slice. Load instruction form kept identical to the proven v2 path.
__device__ __forceinline__ void accum_coh64(const float* __restrict__ AT,
                                            const float* __restrict__ wlds,
                                            float acc[NC]) {
    float a0[8], a1[8];
    #pragma unroll
    for (int j = 0; j < 8; ++j) a0[j] = co_ld(AT + (size_t)j * B_);
    #pragma unroll
    for (int g = 0; g < 8; ++g) {
        const float* cur = (g & 1) ? a1 : a0;
        float*       nxt = (g & 1) ? a0 : a1;
        if (g < 7) {
            #pragma unroll
            for (int j = 0; j < 8; ++j)
                nxt[j] = co_ld(AT + (size_t)((g + 1) * 8 + j) * B_);
        }
        #pragma unroll
        for (int j = 0; j < 8; ++j) {
            const float* wr = wlds + (g * 8 + j) * NC;
            #pragma unroll
            for (int c = 0; c < NC; ++c) acc[c] = fmaf(cur[j], wr[c], acc[c]);
        }
    }
}

// x-projection slice: kn k-values from input row (normal cached float4, v2 form)
__device__ __forceinline__ void accum_x(const float* __restrict__ xrow,
                                        const float* __restrict__ wlds,
                                        int kn, float acc[NC]) {
    #pragma unroll 2
    for (int k = 0; k < kn; k += 4) {
        float4 a = *(const float4*)(xrow + k);
        #pragma unroll
        for (int kk = 0; kk < 4; ++kk) {
            float av = (&a.x)[kk];
            const float* wr = wlds + (k + kk) * NC;
            #pragma unroll
            for (int c = 0; c < NC; ++c) acc[c] = fmaf(av, wr[c], acc[c]);
        }
    }
}

// prologue-only: normal cached loads of state x W_ch
__device__ __forceinline__ void accum_global(const float* __restrict__ Arow,
                                             const float* __restrict__ Wp,
                                             int kn, float acc[NC]) {
    #pragma unroll 2
    for (int k = 0; k < kn; k += 4) {
        float4 a = *(const float4*)(Arow + k);
        const float* w0 = Wp + (size_t)k * H_;
        #pragma unroll
        for (int kk = 0; kk < 4; ++kk) {
            float av = (&a.x)[kk];
            const float* wr = w0 + (size_t)kk * H_;
            #pragma unroll
            for (int c = 0; c < NC; ++c) acc[c] = fmaf(av, wr[c], acc[c]);
        }
    }
}

__device__ __forceinline__ float sigmoidf_(float x) { return 1.0f / (1.0f + expf(-x)); }

// 8-way k-slice reduction: kq>0 write partials, one barrier, kq==0 sums.
// red[s][r][9-pad]: pad -> addr stride 9 per r, gcd(9,32)=1 -> conflict-free.
__device__ __forceinline__ void kq_combine(float acc[NC], float* red, int r, int kq) {
    __syncthreads();                       // protect previous round's reads
    if (kq > 0) {
        float* p = red + ((size_t)(kq - 1) * B_ + r) * 9;
        #pragma unroll
        for (int c = 0; c < NC; ++c) p[c] = acc[c];
    }
    __syncthreads();
    if (kq == 0) {
        #pragma unroll
        for (int s = 0; s < 7; ++s) {
            const float* p = red + ((size_t)s * B_ + r) * 9;
            #pragma unroll
            for (int c = 0; c < NC; ++c) acc[c] += p[c];
        }
    }
}

__global__ __launch_bounds__(NTH, 1) void scagru_persist(
    const float* __restrict__ input, const float* __restrict__ state,
    const float* __restrict__ W_zh, const float* __restrict__ W_zx, const float* __restrict__ b_z,
    const float* __restrict__ W_rh, const float* __restrict__ W_rx, const float* __restrict__ b_r,
    const float* __restrict__ W_hh, const float* __restrict__ W_hx, const float* __restrict__ b_h,
    const float* __restrict__ W_ch, const float* __restrict__ b_c,
    float* __restrict__ out,
    float* __restrict__ hT, float* __restrict__ hrT, float* __restrict__ zT,
    int* __restrict__ bar)
{
    const int w    = blockIdx.x;
    const int gate = w >> 6;          // 0:z 1:r 2:h
    const int cg   = w & 63;
    const int col0 = cg * NC;
    const int tid  = threadIdx.x;
    const int r    = tid & 127;       // batch row
    const int kq   = tid >> 7;        // k-slice 0..7

    __shared__ float wh_lds[H_ * NC];          // 16 KB  [512][8]
    __shared__ float wx_lds[I_ * NC];          // 8 KB   [256][8]
    __shared__ float red[7 * B_ * 9];          // 31.5 KB padded partials

    const float* Wh = (gate == 0) ? W_zh : (gate == 1) ? W_rh : W_hh;
    const float* Wx = (gate == 0) ? W_zx : (gate == 1) ? W_rx : W_hx;
    const float* bg = (gate == 0) ? b_z  : (gate == 1) ? b_r  : b_h;

    int* hslot = bar;          // [64] h-wg cg publishes h_t with value t+1
    int* zslot = bar + 64;     // [64]
    int* rslot = bar + 128;    // [64]

    // ---- stage weight slices into LDS (one time) ----
    for (int i = tid; i < H_ * NC; i += NTH)
        wh_lds[i] = Wh[(size_t)(i >> 3) * H_ + col0 + (i & 7)];
    for (int i = tid; i < I_ * NC; i += NTH)
        wx_lds[i] = Wx[(size_t)(i >> 3) * H_ + col0 + (i & 7)];

    // ---- context slice + fold gate bias (k-slice 64 per thread) ----
    float cctx[NC];
    {
        float acc[NC];
        #pragma unroll
        for (int c = 0; c < NC; ++c) acc[c] = 0.f;
        accum_global(state + (size_t)r * H_ + kq * 64,
                     W_ch + (size_t)(kq * 64) * H_ + col0, 64, acc);
        kq_combine(acc, red, r, kq);
        if (kq == 0) {
            #pragma unroll
            for (int c = 0; c < NC; ++c)
                cctx[c] = fmaxf(acc[c] + b_c[col0 + c], 0.f) + bg[col0 + c];
        }
    }

    // ---- h-wgs publish initial h (transposed, coherent): 1 store/thread ----
    if (gate == 2) {
        co_st(hT + (size_t)(col0 + kq) * B_ + r, state[(size_t)r * H_ + col0 + kq]);
        publish(&hslot[cg], 1);
    }

    // ---- x-projection prefetch for t=0 (k-slice 32 per thread) ----
    float accx[NC];
    #pragma unroll
    for (int c = 0; c < NC; ++c) accx[c] = 0.f;
    accum_x(input + (size_t)r * I_ + kq * 32,
            wx_lds + (size_t)(kq * 32) * NC, 32, accx);

    for (int t = 0; t < T_; ++t) {
        if (gate < 2) {
            // ---------------- phase A: z / r ----------------
            if (tid < 64) {
                const int* s = &hslot[tid];
                while (co_ldi(s) < t + 1) {}
            }
            __syncthreads();

            float hv[NC];
            if (gate == 1 && kq == 0) {      // prefetch h for r*h (hides under GEMM)
                #pragma unroll
                for (int c = 0; c < NC; ++c)
                    hv[c] = co_ld(hT + (size_t)(col0 + c) * B_ + r);
            }
            float acc[NC];
            #pragma unroll
            for (int c = 0; c < NC; ++c) acc[c] = accx[c];
            accum_coh64(hT + (size_t)(kq * 64) * B_ + r,
                        wh_lds + (size_t)(kq * 64) * NC, acc);
            kq_combine(acc, red, r, kq);
            if (kq == 0) {
                if (gate == 0) {
                    #pragma unroll
                    for (int c = 0; c < NC; ++c)
                        co_st(zT + (size_t)(col0 + c) * B_ + r, sigmoidf_(acc[c] + cctx[c]));
                } else {
                    #pragma unroll
                    for (int c = 0; c < NC; ++c)
                        co_st(hrT + (size_t)(col0 + c) * B_ + r,
                              sigmoidf_(acc[c] + cctx[c]) * hv[c]);
                }
            }
            publish(gate == 0 ? &zslot[cg] : &rslot[cg], t + 1);

            if (t + 1 < T_) {
                #pragma unroll
                for (int c = 0; c < NC; ++c) accx[c] = 0.f;
                accum_x(input + (size_t)(t + 1) * B_ * I_ + (size_t)r * I_ + kq * 32,
                        wx_lds + (size_t)(kq * 32) * NC, 32, accx);
            }
        } else {
            // ---------------- phase B: h-candidate + update ----------------
            // WAR: wait for ALL 128 z/r wgs (they read every hT column)
            if (tid < 64) {
                const int* s = &rslot[tid];
                while (co_ldi(s) < t + 1) {}
            } else if (tid < 128) {
                const int* s = &zslot[tid - 64];
                while (co_ldi(s) < t + 1) {}
            }
            __syncthreads();

            float zz[NC], hh[NC];
            if (kq == 0) {                    // prefetch blend operands
                #pragma unroll
                for (int c = 0; c < NC; ++c) {
                    zz[c] = co_ld(zT + (size_t)(col0 + c) * B_ + r);
                    hh[c] = co_ld(hT + (size_t)(col0 + c) * B_ + r);
                }
            }
            float acc[NC];
            #pragma unroll
            for (int c = 0; c < NC; ++c) acc[c] = accx[c];
            accum_coh64(hrT + (size_t)(kq * 64) * B_ + r,
                        wh_lds + (size_t)(kq * 64) * NC, acc);
            kq_combine(acc, red, r, kq);
            if (kq == 0) {
                #pragma unroll
                for (int c = 0; c < NC; ++c) {
                    float hc = tanhf(acc[c] + cctx[c]);
                    float hn = (1.f - zz[c]) * hh[c] + zz[c] * hc;
                    co_st(hT + (size_t)(col0 + c) * B_ + r, hn);
                    if (t == T_ - 1) out[(size_t)r * H_ + col0 + c] = hn;
                }
            }
            publish(&hslot[cg], t + 2);

            if (t + 1 < T_) {
                #pragma unroll
                for (int c = 0; c < NC; ++c) accx[c] = 0.f;
                accum_x(input + (size_t)(t + 1) * B_ * I_ + (size_t)r * I_ + kq * 32,
                        wx_lds + (size_t)(kq * 32) * NC, 32, accx);
            }
        }
    }
}

extern "C" void kernel_launch(void* const* d_in, const int* in_sizes, int n_in,
                              void* d_out, int out_size, void* d_ws, size_t ws_size,
                              hipStream_t stream)
{
    const float* input = (const float*)d_in[0];
    const float* state = (const float*)d_in[1];
    const float* W_zh  = (const float*)d_in[2];
    const float* W_zx  = (const float*)d_in[3];
    const float* b_z   = (const float*)d_in[4];
    const float* W_rh  = (const float*)d_in[5];
    const float* W_rx  = (const float*)d_in[6];
    const float* b_r   = (const float*)d_in[7];
    const float* W_hh  = (const float*)d_in[8];
    const float* W_hx  = (const float*)d_in[9];
    const float* b_h   = (const float*)d_in[10];
    const float* W_ch  = (const float*)d_in[11];
    const float* b_c   = (const float*)d_in[12];

    float* out = (float*)d_out;
    float* ws  = (float*)d_ws;

    const size_t HB = (size_t)H_ * B_;           // 65536
    float* hT  = ws;
    float* hrT = ws + HB;
    float* zT  = ws + 2 * HB;
    int*   bar = (int*)((char*)d_ws + 3 * HB * sizeof(float));

    hipMemsetAsync(bar, 0, 1024, stream);

    scagru_persist<<<dim3(NWG), dim3(NTH), 0, stream>>>(
        input, state,
        W_zh, W_zx, b_z, W_rh, W_rx, b_r, W_hh, W_hx, b_h, W_ch, b_c,
        out, hT, hrT, zT, bar);
}

// Round 7
// 11282.610 us; speedup vs baseline: 4.5897x; 4.5897x over previous
//
#include <hip/hip_runtime.h>
#include <math.h>

#define T_    1024
#define B_    128
#define H_    512
#define I_    256
#define NTH   256
#define NC    16      // cols per wg
#define NCG   32      // col-groups per gate
#define RROWS 64      // rows per rowset
#define NWG   192     // 2 rowsets x 3 gates x 32 cgs

typedef __attribute__((ext_vector_type(8))) short short8;
typedef __attribute__((ext_vector_type(4))) float f32x4;

// ---- coherent (cross-XCD) accesses: per-access, no cache-wide fences, no RMW ----
__device__ __forceinline__ unsigned long long co_ld8(const void* p) {
    return __hip_atomic_load((const unsigned long long*)p, __ATOMIC_RELAXED, __HIP_MEMORY_SCOPE_AGENT);
}
__device__ __forceinline__ void co_st8(void* p, unsigned long long v) {
    __hip_atomic_store((unsigned long long*)p, v, __ATOMIC_RELAXED, __HIP_MEMORY_SCOPE_AGENT);
}
__device__ __forceinline__ int co_ldi(const int* p) {
    return __hip_atomic_load(p, __ATOMIC_RELAXED, __HIP_MEMORY_SCOPE_AGENT);
}
__device__ __forceinline__ void co_sti(int* p, int v) {
    __hip_atomic_store(p, v, __ATOMIC_RELAXED, __HIP_MEMORY_SCOPE_AGENT);
}

__device__ __forceinline__ unsigned short f2bf(float f) {   // RNE
    unsigned u = __float_as_uint(f);
    return (unsigned short)((u + 0x7FFFu + ((u >> 16) & 1u)) >> 16);
}
__device__ __forceinline__ float bf2f(unsigned short s) {
    return __uint_as_float(((unsigned)s) << 16);
}
__device__ __forceinline__ unsigned long long pack4(const float v[4]) {
    return (unsigned long long)f2bf(v[0]) | ((unsigned long long)f2bf(v[1]) << 16)
         | ((unsigned long long)f2bf(v[2]) << 32) | ((unsigned long long)f2bf(v[3]) << 48);
}
__device__ __forceinline__ void unpack4(unsigned long long u, float v[4]) {
    v[0] = bf2f((unsigned short)u);        v[1] = bf2f((unsigned short)(u >> 16));
    v[2] = bf2f((unsigned short)(u >> 32)); v[3] = bf2f((unsigned short)(u >> 48));
}
__device__ __forceinline__ float sigmoidf_(float x) { return 1.0f / (1.0f + expf(-x)); }

// publish: __syncthreads() drains vmcnt (sc1 data stores at coherence point),
// leader then writes this wg's OWN slot (plain sc1 store).  [R5-proven]
__device__ __forceinline__ void publish(int* slot, int v) {
    __syncthreads();
    if (threadIdx.x == 0) co_sti(slot, v);
}

// stage 64 rows x 512 bf16 (64 KB) exchange panel -> XOR-swizzled LDS
// coalesced 8-B coherent loads, depth-8 batches
__device__ __forceinline__ void stage_rows(char* ast, const unsigned short* src, int tid) {
    #pragma unroll
    for (int it = 0; it < 4; ++it) {
        unsigned long long v[8];
        #pragma unroll
        for (int j = 0; j < 8; ++j) {
            int u = ((it * 8 + j) * NTH + tid) * 8;
            v[j] = co_ld8((const char*)src + u);
        }
        #pragma unroll
        for (int j = 0; j < 8; ++j) {
            int u = ((it * 8 + j) * NTH + tid) * 8;
            int row = u >> 10;                       // 1024 B per row
            *(unsigned long long*)(ast + (u ^ ((row & 7) << 4))) = v[j];
        }
    }
}

// x-projection + context fold: xacc[r][c] = x_t[r,:] @ Wx[:,c] + cctx[r][c]
// thread map (r = tid&63, cq = tid>>6): 4 cols, full K=256, no combine
__device__ __forceinline__ void compute_xacc(const float* xt, int r0,
                                             const float* wx, const float* cctx,
                                             float* xacc, int tid) {
    const int r = tid & 63, cq = tid >> 6;
    const float* xrow = xt + (size_t)(r0 + r) * I_;
    f32x4 acc = *(const f32x4*)(cctx + r * 20 + cq * 4);
    #pragma unroll 4
    for (int k = 0; k < I_; k += 4) {
        f32x4 xv = *(const f32x4*)(xrow + k);
        #pragma unroll
        for (int kk = 0; kk < 4; ++kk) {
            f32x4 wr = *(const f32x4*)(wx + (k + kk) * NC + cq * 4);
            #pragma unroll
            for (int q = 0; q < 4; ++q) acc[q] = fmaf(xv[kk], wr[q], acc[q]);
        }
    }
    *(f32x4*)(xacc + r * 20 + cq * 4) = acc;
}

__global__ __launch_bounds__(NTH, 1) void scagru_mfma(
    const float* __restrict__ input, const float* __restrict__ state,
    const float* __restrict__ W_zh, const float* __restrict__ W_zx, const float* __restrict__ b_z,
    const float* __restrict__ W_rh, const float* __restrict__ W_rx, const float* __restrict__ b_r,
    const float* __restrict__ W_hh, const float* __restrict__ W_hx, const float* __restrict__ b_h,
    const float* __restrict__ W_ch, const float* __restrict__ b_c,
    float* __restrict__ out,
    unsigned short* __restrict__ hT, unsigned short* __restrict__ hrT,
    unsigned short* __restrict__ zT, int* __restrict__ bar)
{
    const int wgid = blockIdx.x;
    const int rs   = wgid & 1;
    const int gate = (wgid >> 1) % 3;          // 0:z 1:r 2:h
    const int cg   = wgid / 6;                 // 0..31
    const int c0   = cg * NC;
    const int r0   = rs * RROWS;
    const int tid  = threadIdx.x;
    const int lane = tid & 63;
    const int wv   = tid >> 6;

    __shared__ __align__(16) char  astage[RROWS * H_ * 2];   // 64 KB bf16, swizzled
    __shared__ __align__(16) char  wfrag[16 * 1024];         // 16 KB Wg^T A-frags
    __shared__ float wx[I_ * NC];                            // 16 KB fp32 [k][c]
    __shared__ float cctx[RROWS * 20];                       // padded stride 20
    __shared__ float xacc[RROWS * 20];

    const float* Wh = (gate == 0) ? W_zh : (gate == 1) ? W_rh : W_hh;
    const float* Wx = (gate == 0) ? W_zx : (gate == 1) ? W_rx : W_hx;
    const float* bg = (gate == 0) ? b_z  : (gate == 1) ? b_r  : b_h;

    int* hslot = bar;            // [64]: rs*NCG+cg ; value t+1 == h_t ready (init h_0 -> 1)
    int* zslot = bar + 64;
    int* rslot = bar + 128;

    // ---- one-time: Wh^T as contiguous A-frags (lane l: m=l&15, k=kt*32+(l>>4)*8+j) ----
    #pragma unroll
    for (int it = 0; it < 4; ++it) {
        const int kt = it * 4 + wv;
        const int m  = lane & 15, kg = lane >> 4;
        short8 a;
        #pragma unroll
        for (int j = 0; j < 8; ++j) {
            int k = kt * 32 + kg * 8 + j;
            a[j] = (short)f2bf(Wh[(size_t)k * H_ + c0 + m]);
        }
        *(short8*)(wfrag + kt * 1024 + lane * 16) = a;
    }
    // ---- one-time: Wx fp32 [k][c] ----
    for (int i = tid; i < I_ * NC; i += NTH)
        wx[i] = Wx[(size_t)(i >> 4) * H_ + c0 + (i & 15)];

    // ---- one-time: cctx[r][c] = relu(state@W_ch + b_c) + b_gate ----
    {
        const int r = tid & 63, cq = tid >> 6;
        const float* srow = state + (size_t)(r0 + r) * H_;
        float acc[4] = {0.f, 0.f, 0.f, 0.f};
        #pragma unroll 4
        for (int k = 0; k < H_; ++k) {
            float sv = srow[k];
            const float* wr = W_ch + (size_t)k * H_ + c0 + cq * 4;
            #pragma unroll
            for (int q = 0; q < 4; ++q) acc[q] = fmaf(sv, wr[q], acc[q]);
        }
        f32x4 cc;
        #pragma unroll
        for (int q = 0; q < 4; ++q)
            cc[q] = fmaxf(acc[q] + b_c[c0 + cq * 4 + q], 0.f) + bg[c0 + cq * 4 + q];
        *(f32x4*)(cctx + r * 20 + cq * 4) = cc;
    }
    __syncthreads();

    // C-frag mapping (verified m89): D row m=(lane>>4)*4+reg -> hidden col, col n=lane&15 -> batch row
    const int n  = lane & 15, m0 = (lane >> 4) * 4;
    const int row_rel = wv * 16 + n;                 // 0..63
    const int grow    = r0 + row_rel;                // global batch row

    // ---- h-gang: init fp32 private h + publish bf16 h_0 ----
    float hprev[4] = {0.f, 0.f, 0.f, 0.f};
    if (gate == 2) {
        f32x4 s = *(const f32x4*)(state + (size_t)grow * H_ + c0 + m0);
        float v[4];
        #pragma unroll
        for (int q = 0; q < 4; ++q) { hprev[q] = s[q]; v[q] = s[q]; }
        co_st8(hT + (size_t)grow * H_ + c0 + m0, pack4(v));
        publish(&hslot[rs * NCG + cg], 1);
    }

    // ---- xacc for t=0 ----
    compute_xacc(input, r0, wx, cctx, xacc, tid);

    const int rowbase = row_rel << 10;
    const int swz     = (row_rel & 7) << 4;

    for (int t = 0; t < T_; ++t) {
        if (gate < 2) {
            // ================= phase A: z / r =================
            if (tid < 32) {
                const int* s = &hslot[rs * NCG + tid];
                while (co_ldi(s) < t + 1) __builtin_amdgcn_s_sleep(1);
            }
            __syncthreads();
            stage_rows(astage, hT + (size_t)r0 * H_, tid);
            __syncthreads();

            f32x4 acc = {0.f, 0.f, 0.f, 0.f};
            #pragma unroll
            for (int kt = 0; kt < 16; ++kt) {
                short8 a = *(const short8*)(wfrag + kt * 1024 + lane * 16);
                int off = rowbase + ((kt * 32 + (lane >> 4) * 8) << 1);
                short8 b = *(const short8*)(astage + (off ^ swz));
                acc = __builtin_amdgcn_mfma_f32_16x16x32_bf16(a, b, acc, 0, 0, 0);
            }

            f32x4 xa = *(const f32x4*)(xacc + row_rel * 20 + m0);
            float v[4];
            if (gate == 0) {
                #pragma unroll
                for (int q = 0; q < 4; ++q) v[q] = sigmoidf_(acc[q] + xa[q]);
                co_st8(zT + (size_t)grow * H_ + c0 + m0, pack4(v));
                publish(&zslot[rs * NCG + cg], t + 1);
            } else {
                int hb = (rowbase + ((c0 + m0) << 1)) ^ swz;
                float hv[4];
                unpack4(*(const unsigned long long*)(astage + hb), hv);
                #pragma unroll
                for (int q = 0; q < 4; ++q) v[q] = sigmoidf_(acc[q] + xa[q]) * hv[q];
                co_st8(hrT + (size_t)grow * H_ + c0 + m0, pack4(v));
                publish(&rslot[rs * NCG + cg], t + 1);
            }
            if (t + 1 < T_)
                compute_xacc(input + (size_t)(t + 1) * B_ * I_, r0, wx, cctx, xacc, tid);
        } else {
            // ================= phase B: h-candidate + update =================
            if (tid < 64) {
                const int* s = (tid < 32) ? &zslot[rs * NCG + tid] : &rslot[rs * NCG + tid - 32];
                while (co_ldi(s) < t + 1) __builtin_amdgcn_s_sleep(1);
            }
            __syncthreads();
            stage_rows(astage, hrT + (size_t)r0 * H_, tid);
            __syncthreads();

            f32x4 acc = {0.f, 0.f, 0.f, 0.f};
            #pragma unroll
            for (int kt = 0; kt < 16; ++kt) {
                short8 a = *(const short8*)(wfrag + kt * 1024 + lane * 16);
                int off = rowbase + ((kt * 32 + (lane >> 4) * 8) << 1);
                short8 b = *(const short8*)(astage + (off ^ swz));
                acc = __builtin_amdgcn_mfma_f32_16x16x32_bf16(a, b, acc, 0, 0, 0);
            }

            f32x4 xa = *(const f32x4*)(xacc + row_rel * 20 + m0);
            float zz[4];
            unpack4(co_ld8(zT + (size_t)grow * H_ + c0 + m0), zz);
            float hn[4];
            #pragma unroll
            for (int q = 0; q < 4; ++q) {
                float hc = tanhf(acc[q] + xa[q]);
                hn[q] = (1.f - zz[q]) * hprev[q] + zz[q] * hc;
                hprev[q] = hn[q];
            }
            co_st8(hT + (size_t)grow * H_ + c0 + m0, pack4(hn));
            if (t == T_ - 1)
                *(float4*)(out + (size_t)grow * H_ + c0 + m0) =
                    make_float4(hn[0], hn[1], hn[2], hn[3]);
            publish(&hslot[rs * NCG + cg], t + 2);

            if (t + 1 < T_)
                compute_xacc(input + (size_t)(t + 1) * B_ * I_, r0, wx, cctx, xacc, tid);
        }
    }
}

extern "C" void kernel_launch(void* const* d_in, const int* in_sizes, int n_in,
                              void* d_out, int out_size, void* d_ws, size_t ws_size,
                              hipStream_t stream)
{
    const float* input = (const float*)d_in[0];
    const float* state = (const float*)d_in[1];
    const float* W_zh  = (const float*)d_in[2];
    const float* W_zx  = (const float*)d_in[3];
    const float* b_z   = (const float*)d_in[4];
    const float* W_rh  = (const float*)d_in[5];
    const float* W_rx  = (const float*)d_in[6];
    const float* b_r   = (const float*)d_in[7];
    const float* W_hh  = (const float*)d_in[8];
    const float* W_hx  = (const float*)d_in[9];
    const float* b_h   = (const float*)d_in[10];
    const float* W_ch  = (const float*)d_in[11];
    const float* b_c   = (const float*)d_in[12];

    float* out = (float*)d_out;
    char*  ws  = (char*)d_ws;

    const size_t PB = (size_t)B_ * H_ * sizeof(unsigned short);  // 128 KB per panel
    unsigned short* hT  = (unsigned short*)(ws);
    unsigned short* hrT = (unsigned short*)(ws + PB);
    unsigned short* zT  = (unsigned short*)(ws + 2 * PB);
    int*            bar = (int*)(ws + 3 * PB);

    hipMemsetAsync(bar, 0, 1024, stream);

    scagru_mfma<<<dim3(NWG), dim3(NTH), 0, stream>>>(
        input, state,
        W_zh, W_zx, b_z, W_rh, W_rx, b_r, W_hh, W_hx, b_h, W_ch, b_c,
        out, hT, hrT, zT, bar);
}

// Round 8
// 7170.914 us; speedup vs baseline: 7.2214x; 1.5734x over previous
//
#include <hip/hip_runtime.h>
#include <math.h>

#define T_    1024
#define B_    128
#define H_    512
#define I_    256
#define NTH   1024
#define NC    16      // cols per wg
#define NCG   32      // col-groups
#define RROWS 64      // rows per rowset
#define NWG   128     // 2 rowsets x 2 kinds (zr, h) x 32 cgs

typedef __attribute__((ext_vector_type(8))) short short8;
typedef __attribute__((ext_vector_type(4))) float f32x4;

// ---- shared memory layout (bytes) ----
#define OF_WA    65536          // 16 KB A-frags: W_zh (zr) / W_hh (h)
#define OF_WB    81920          // 16 KB A-frags: W_rh (zr only)
#define OF_WX    98304          // 16 KB A-frags: W_zx|W_rx (zr) / W_hx (h)
#define OF_CCTX  114688         // 9216 B: [64][36] f32  (ctx + gate bias)
#define OF_XACC  123904         // 9216 B: [64][36] f32  (x@Wx + cctx)
#define SMEM_SZ  133120

// ---- coherent (cross-XCD) accesses: per-access, no cache-wide fences, no RMW ----
__device__ __forceinline__ unsigned long long co_ld8(const void* p) {
    return __hip_atomic_load((const unsigned long long*)p, __ATOMIC_RELAXED, __HIP_MEMORY_SCOPE_AGENT);
}
__device__ __forceinline__ void co_st8(void* p, unsigned long long v) {
    __hip_atomic_store((unsigned long long*)p, v, __ATOMIC_RELAXED, __HIP_MEMORY_SCOPE_AGENT);
}
__device__ __forceinline__ int co_ldi(const int* p) {
    return __hip_atomic_load(p, __ATOMIC_RELAXED, __HIP_MEMORY_SCOPE_AGENT);
}
__device__ __forceinline__ void co_sti(int* p, int v) {
    __hip_atomic_store(p, v, __ATOMIC_RELAXED, __HIP_MEMORY_SCOPE_AGENT);
}

__device__ __forceinline__ unsigned short f2bf(float f) {   // RNE
    unsigned u = __float_as_uint(f);
    return (unsigned short)((u + 0x7FFFu + ((u >> 16) & 1u)) >> 16);
}
__device__ __forceinline__ float bf2f(unsigned short s) {
    return __uint_as_float(((unsigned)s) << 16);
}
__device__ __forceinline__ unsigned long long pack4(const float v[4]) {
    return (unsigned long long)f2bf(v[0]) | ((unsigned long long)f2bf(v[1]) << 16)
         | ((unsigned long long)f2bf(v[2]) << 32) | ((unsigned long long)f2bf(v[3]) << 48);
}
__device__ __forceinline__ void unpack4(unsigned long long u, float v[4]) {
    v[0] = bf2f((unsigned short)u);         v[1] = bf2f((unsigned short)(u >> 16));
    v[2] = bf2f((unsigned short)(u >> 32)); v[3] = bf2f((unsigned short)(u >> 48));
}
__device__ __forceinline__ float sigmoidf_(float x) { return 1.0f / (1.0f + expf(-x)); }

// publish: __syncthreads() drains vmcnt (sc1 data stores at coherence point),
// then leader writes this wg's OWN slot. [R5/R7-proven]
__device__ __forceinline__ void publish(int* slot, int v) {
    __syncthreads();
    if (threadIdx.x == 0) co_sti(slot, v);
}

// stage 64x512 bf16 exchange panel (64 KB) -> XOR-swizzled LDS; one depth-8 batch
__device__ __forceinline__ void stage_panel(char* ast, const unsigned short* src, int tid) {
    unsigned long long v[8];
    #pragma unroll
    for (int j = 0; j < 8; ++j) {
        int u = (j * NTH + tid) * 8;
        v[j] = co_ld8((const char*)src + u);
    }
    #pragma unroll
    for (int j = 0; j < 8; ++j) {
        int u = (j * NTH + tid) * 8;
        int row = u >> 10;                                  // 1024 B per row
        *(unsigned long long*)(ast + (u ^ ((row & 7) << 4))) = v[j];
    }
}

// stage 64x256 fp32 x-panel -> bf16 swizzled LDS (32 KB), rows of 512 B
__device__ __forceinline__ void stage_x(char* ast, const float* xpanel, int tid) {
    const float4* src = (const float4*)xpanel + tid * 4;    // 16 floats / thread
    float4 f[4];
    #pragma unroll
    for (int j = 0; j < 4; ++j) f[j] = src[j];
    const int row = tid >> 4;
    const int ub  = row * 512 + (tid & 15) * 32;
    const int s   = (row & 7) << 4;
    #pragma unroll
    for (int j = 0; j < 4; ++j) {
        float v[4] = {f[j].x, f[j].y, f[j].z, f[j].w};
        *(unsigned long long*)(ast + ((ub + j * 8) ^ s)) = pack4(v);
    }
}

__global__ __launch_bounds__(NTH, 1) void scagru_fused(
    const float* __restrict__ input, const float* __restrict__ state,
    const float* __restrict__ W_zh, const float* __restrict__ W_zx, const float* __restrict__ b_z,
    const float* __restrict__ W_rh, const float* __restrict__ W_rx, const float* __restrict__ b_r,
    const float* __restrict__ W_hh, const float* __restrict__ W_hx, const float* __restrict__ b_h,
    const float* __restrict__ W_ch, const float* __restrict__ b_c,
    float* __restrict__ out,
    unsigned short* __restrict__ hT, unsigned short* __restrict__ hrT,
    unsigned short* __restrict__ zT, int* __restrict__ bar)
{
    const int wgid = blockIdx.x;
    const int rs   = wgid & 1;
    const int kind = (wgid >> 1) & 1;          // 0 = zr, 1 = h
    const int cg   = wgid >> 2;                // 0..31
    const int c0   = cg * NC;
    const int r0   = rs * RROWS;
    const int tid  = threadIdx.x;
    const int lane = tid & 63;
    const int wv   = tid >> 6;                 // 0..15
    const int n    = lane & 15;
    const int kg   = lane >> 4;
    const int m0   = kg * 4;

    __shared__ __align__(16) char smem[SMEM_SZ];
    char*  ast  = smem;
    char*  wA   = smem + OF_WA;
    char*  wB   = smem + OF_WB;
    char*  wX   = smem + OF_WX;
    float* cctx = (float*)(smem + OF_CCTX);
    float* xacc = (float*)(smem + OF_XACC);

    int* hslot  = bar;          // [64]: value t+1 == h_t published
    int* zrslot = bar + 64;     // [64]: value t+1 == z,hr of step t published

    // ---- one-time: A-frags (lane: m=lane&15 -> hidden col, k=kt*32+kg*8+j) ----
    {
        const float* W = kind ? W_hh : W_zh;
        const int kt = wv;
        short8 a;
        #pragma unroll
        for (int j = 0; j < 8; ++j)
            a[j] = (short)f2bf(W[(size_t)(kt * 32 + kg * 8 + j) * H_ + c0 + n]);
        *(short8*)(wA + kt * 1024 + lane * 16) = a;
    }
    if (!kind) {
        const int kt = wv;
        short8 a;
        #pragma unroll
        for (int j = 0; j < 8; ++j)
            a[j] = (short)f2bf(W_rh[(size_t)(kt * 32 + kg * 8 + j) * H_ + c0 + n]);
        *(short8*)(wB + kt * 1024 + lane * 16) = a;
    }
    if (!kind) {                                 // W_zx | W_rx  (K=256: kt 0..7)
        const int g = wv >> 3, kt = wv & 7;
        const float* W = g ? W_rx : W_zx;
        short8 a;
        #pragma unroll
        for (int j = 0; j < 8; ++j)
            a[j] = (short)f2bf(W[(size_t)(kt * 32 + kg * 8 + j) * H_ + c0 + n]);
        *(short8*)(wX + g * 8192 + kt * 1024 + lane * 16) = a;
    } else if (wv < 8) {                         // W_hx
        const int kt = wv;
        short8 a;
        #pragma unroll
        for (int j = 0; j < 8; ++j)
            a[j] = (short)f2bf(W_hx[(size_t)(kt * 32 + kg * 8 + j) * H_ + c0 + n]);
        *(short8*)(wX + kt * 1024 + lane * 16) = a;
    }

    // ---- one-time: cctx[r][gcol] = relu(state@W_ch+b_c)[r, col] + b_gate[col] ----
    {
        const int r = tid & 63, cq = tid >> 6;
        const float* srow = state + (size_t)(r0 + r) * H_;
        const int ng = kind ? 1 : 2;
        for (int p = 0; p < ng; ++p) {
            const int gcol = kind ? cq : cq * 2 + p;
            const int col  = c0 + (gcol & 15);
            float acc = 0.f;
            #pragma unroll 4
            for (int k = 0; k < H_; ++k)
                acc = fmaf(srow[k], W_ch[(size_t)k * H_ + col], acc);
            const float* bgp = kind ? b_h : (gcol < 16 ? b_z : b_r);
            cctx[r * 36 + gcol] = fmaxf(acc + b_c[col], 0.f) + bgp[col];
        }
    }
    __syncthreads();

    // ---- h wgs: fp32 private h state + publish bf16 h_0 ----
    float hp[4] = {0.f, 0.f, 0.f, 0.f};
    if (kind) {
        if (wv < 4) {
            const int row_rel = wv * 16 + n, grow = r0 + row_rel;
            f32x4 s = *(const f32x4*)(state + (size_t)grow * H_ + c0 + m0);
            float v[4];
            #pragma unroll
            for (int q = 0; q < 4; ++q) { hp[q] = s[q]; v[q] = s[q]; }
            co_st8(hT + (size_t)grow * H_ + c0 + m0, pack4(v));
        }
        publish(&hslot[rs * NCG + cg], 1);
    }

    // ---- x-projection for t=0 (both kinds): stage x -> MFMA (C init = cctx) ----
    stage_x(ast, input + (size_t)r0 * I_, tid);
    __syncthreads();
    {
        const int nact = kind ? 4 : 8;
        if (wv < nact) {
            const int g = kind ? 0 : (wv >> 2);
            const int rt = wv & 3;
            const int row_rel = rt * 16 + n;
            const int swz = (row_rel & 7) << 4;
            f32x4 acc = *(const f32x4*)(cctx + row_rel * 36 + g * 16 + m0);
            #pragma unroll
            for (int kt = 0; kt < 8; ++kt) {
                short8 a = *(const short8*)(wX + g * 8192 + kt * 1024 + lane * 16);
                short8 b = *(const short8*)(ast + ((row_rel * 512 + ((kt * 32 + kg * 8) << 1)) ^ swz));
                acc = __builtin_amdgcn_mfma_f32_16x16x32_bf16(a, b, acc, 0, 0, 0);
            }
            *(f32x4*)(xacc + row_rel * 36 + g * 16 + m0) = acc;
        }
    }
    __syncthreads();

    for (int t = 0; t < T_; ++t) {
        if (!kind) {
            // ================= phase A: z & r =================
            if (tid < NCG) {
                const int* s = &hslot[rs * NCG + tid];
                while (co_ldi(s) < t + 1) __builtin_amdgcn_s_sleep(1);
            }
            __syncthreads();
            stage_panel(ast, hT + (size_t)r0 * H_, tid);
            __syncthreads();

            if (wv < 8) {
                const int g = wv >> 2, rt = wv & 3;
                const int row_rel = rt * 16 + n, grow = r0 + row_rel;
                const int swz = (row_rel & 7) << 4;
                const char* wf = g ? wB : wA;
                f32x4 acc = *(const f32x4*)(xacc + row_rel * 36 + g * 16 + m0);
                #pragma unroll
                for (int kt = 0; kt < 16; ++kt) {
                    short8 a = *(const short8*)(wf + kt * 1024 + lane * 16);
                    short8 b = *(const short8*)(ast + ((row_rel * 1024 + ((kt * 32 + kg * 8) << 1)) ^ swz));
                    acc = __builtin_amdgcn_mfma_f32_16x16x32_bf16(a, b, acc, 0, 0, 0);
                }
                float v[4];
                if (g == 0) {
                    #pragma unroll
                    for (int q = 0; q < 4; ++q) v[q] = sigmoidf_(acc[q]);
                    co_st8(zT + (size_t)grow * H_ + c0 + m0, pack4(v));
                } else {
                    float hv[4];
                    unpack4(*(const unsigned long long*)(ast + ((row_rel * 1024 + ((c0 + m0) << 1)) ^ swz)), hv);
                    #pragma unroll
                    for (int q = 0; q < 4; ++q) v[q] = sigmoidf_(acc[q]) * hv[q];
                    co_st8(hrT + (size_t)grow * H_ + c0 + m0, pack4(v));
                }
            }
            publish(&zrslot[rs * NCG + cg], t + 1);
        } else {
            // ================= phase B: h-candidate + update =================
            if (tid < NCG) {
                const int* s = &zrslot[rs * NCG + tid];
                while (co_ldi(s) < t + 1) __builtin_amdgcn_s_sleep(1);
            }
            __syncthreads();
            stage_panel(ast, hrT + (size_t)r0 * H_, tid);
            __syncthreads();

            if (wv < 4) {
                const int rt = wv;
                const int row_rel = rt * 16 + n, grow = r0 + row_rel;
                const int swz = (row_rel & 7) << 4;
                unsigned long long zpk = co_ld8(zT + (size_t)grow * H_ + c0 + m0);  // prefetch
                f32x4 acc = *(const f32x4*)(xacc + row_rel * 36 + m0);
                #pragma unroll
                for (int kt = 0; kt < 16; ++kt) {
                    short8 a = *(const short8*)(wA + kt * 1024 + lane * 16);
                    short8 b = *(const short8*)(ast + ((row_rel * 1024 + ((kt * 32 + kg * 8) << 1)) ^ swz));
                    acc = __builtin_amdgcn_mfma_f32_16x16x32_bf16(a, b, acc, 0, 0, 0);
                }
                float zz[4], hn[4];
                unpack4(zpk, zz);
                #pragma unroll
                for (int q = 0; q < 4; ++q) {
                    float hc = tanhf(acc[q]);
                    hn[q] = (1.f - zz[q]) * hp[q] + zz[q] * hc;
                    hp[q] = hn[q];
                }
                co_st8(hT + (size_t)grow * H_ + c0 + m0, pack4(hn));
                if (t == T_ - 1)
                    *(float4*)(out + (size_t)grow * H_ + c0 + m0) =
                        make_float4(hn[0], hn[1], hn[2], hn[3]);
            }
            publish(&hslot[rs * NCG + cg], t + 2);
        }

        // ---- x-projection for t+1 (hidden after publish; astage is free) ----
        if (t + 1 < T_) {
            stage_x(ast, input + ((size_t)(t + 1) * B_ + r0) * I_, tid);
            __syncthreads();
            const int nact = kind ? 4 : 8;
            if (wv < nact) {
                const int g = kind ? 0 : (wv >> 2);
                const int rt = wv & 3;
                const int row_rel = rt * 16 + n;
                const int swz = (row_rel & 7) << 4;
                f32x4 acc = *(const f32x4*)(cctx + row_rel * 36 + g * 16 + m0);
                #pragma unroll
                for (int kt = 0; kt < 8; ++kt) {
                    short8 a = *(const short8*)(wX + g * 8192 + kt * 1024 + lane * 16);
                    short8 b = *(const short8*)(ast + ((row_rel * 512 + ((kt * 32 + kg * 8) << 1)) ^ swz));
                    acc = __builtin_amdgcn_mfma_f32_16x16x32_bf16(a, b, acc, 0, 0, 0);
                }
                *(f32x4*)(xacc + row_rel * 36 + g * 16 + m0) = acc;
            }
        }
    }
}

extern "C" void kernel_launch(void* const* d_in, const int* in_sizes, int n_in,
                              void* d_out, int out_size, void* d_ws, size_t ws_size,
                              hipStream_t stream)
{
    const float* input = (const float*)d_in[0];
    const float* state = (const float*)d_in[1];
    const float* W_zh  = (const float*)d_in[2];
    const float* W_zx  = (const float*)d_in[3];
    const float* b_z   = (const float*)d_in[4];
    const float* W_rh  = (const float*)d_in[5];
    const float* W_rx  = (const float*)d_in[6];
    const float* b_r   = (const float*)d_in[7];
    const float* W_hh  = (const float*)d_in[8];
    const float* W_hx  = (const float*)d_in[9];
    const float* b_h   = (const float*)d_in[10];
    const float* W_ch  = (const float*)d_in[11];
    const float* b_c   = (const float*)d_in[12];

    float* out = (float*)d_out;
    char*  ws  = (char*)d_ws;

    const size_t PB = (size_t)B_ * H_ * sizeof(unsigned short);  // 128 KB / panel
    unsigned short* hT  = (unsigned short*)(ws);
    unsigned short* hrT = (unsigned short*)(ws + PB);
    unsigned short* zT  = (unsigned short*)(ws + 2 * PB);
    int*            bar = (int*)(ws + 3 * PB);

    hipMemsetAsync(bar, 0, 1024, stream);

    scagru_fused<<<dim3(NWG), dim3(NTH), 0, stream>>>(
        input, state,
        W_zh, W_zx, b_z, W_rh, W_rx, b_r, W_hh, W_hx, b_h, W_ch, b_c,
        out, hT, hrT, zT, bar);
}

// Round 10
// 4163.185 us; speedup vs baseline: 12.4386x; 1.7225x over previous
//
#include <hip/hip_runtime.h>
#include <math.h>

#define T_    1024
#define B_    128
#define H_    512
#define I_    256
#define NTH   512
#define NC    16      // cols per wg
#define NCG   32      // wgs per rowset (= CUs per XCD)
#define RR    16      // rows per rowset (8 rowsets x 16 = 128)
#define NWG   256
#define CAP   1000000

typedef __attribute__((ext_vector_type(8))) short short8;
typedef __attribute__((ext_vector_type(4))) float f32x4;

// ---- LDS layout (bytes) ----
#define OF_WZH 16384              // 16 KB A-frags W_zh   (ast = 0..16384)
#define OF_WRH 32768              // 16 KB W_rh
#define OF_WHH 49152              // 16 KB W_hh
#define OF_WZX 65536              // 8 KB  W_zx
#define OF_WRX 73728              // 8 KB  W_rx
#define OF_WHX 81920              // 8 KB  W_hx
#define OF_CB  90112              // [16][17] f32 ctx base
#define SMEM_SZ 91232             // ~89 KB > 80 KB -> exactly 1 wg/CU

__device__ __forceinline__ unsigned short f2bf(float f) {   // RNE
    unsigned u = __float_as_uint(f);
    return (unsigned short)((u + 0x7FFFu + ((u >> 16) & 1u)) >> 16);
}
__device__ __forceinline__ float bf2f(unsigned short s) {
    return __uint_as_float(((unsigned)s) << 16);
}
__device__ __forceinline__ unsigned long long pack4(const float v[4]) {
    return (unsigned long long)f2bf(v[0]) | ((unsigned long long)f2bf(v[1]) << 16)
         | ((unsigned long long)f2bf(v[2]) << 32) | ((unsigned long long)f2bf(v[3]) << 48);
}
__device__ __forceinline__ void unpack4(unsigned long long u, float v[4]) {
    v[0] = bf2f((unsigned short)u);         v[1] = bf2f((unsigned short)(u >> 16));
    v[2] = bf2f((unsigned short)(u >> 32)); v[3] = bf2f((unsigned short)(u >> 48));
}
__device__ __forceinline__ float sigmoidf_(float x) { return 1.0f / (1.0f + expf(-x)); }

// XCD-local wait: L1-only invalidate (L1 is write-through -> never dirty ->
// nothing lost) then plain load hits the local L2 where same-XCD producers'
// write-through stores land. Capped: on breakdown we fail FAST, not hang.
__device__ __forceinline__ void wait_local(volatile const int* f, int tgt, bool& dead) {
    if (dead) return;
    int it = 0;
    while (1) {
        asm volatile("buffer_inv sc0" ::: "memory");
        int v = *f;
        if (v >= tgt) break;
        if (++it > CAP) { dead = true; break; }
    }
}

// stage 16x512 bf16 panel (16 KB) from local L2 -> XOR-swizzled LDS
__device__ __forceinline__ void stage_panel(char* ast, const unsigned short* src, int tid) {
    asm volatile("buffer_inv sc0" ::: "memory");
    const char* s = (const char*)src;
    const int u0 = tid * 32;
    uint4 a = *(const uint4*)(s + u0);
    uint4 b = *(const uint4*)(s + u0 + 16);
    const int row = u0 >> 10;                 // 1024 B per row
    const int sw  = (row & 7) << 4;
    *(uint4*)(ast + (u0 ^ sw))        = a;
    *(uint4*)(ast + ((u0 + 16) ^ sw)) = b;
}

// stage 16x256 fp32 x rows -> bf16 swizzled LDS (rows of 512 B); cached loads
__device__ __forceinline__ void stage_x(char* ast, const float* xp, int tid) {
    const int row = tid >> 5, seg = tid & 31;
    const float* p = xp + (size_t)row * I_ + seg * 8;
    float4 f0 = *(const float4*)p, f1 = *(const float4*)(p + 4);
    float v0[4] = {f0.x, f0.y, f0.z, f0.w};
    float v1[4] = {f1.x, f1.y, f1.z, f1.w};
    const int ub = row * 512 + seg * 16;
    const int sw = (row & 7) << 4;
    *(unsigned long long*)(ast + (ub ^ sw))       = pack4(v0);
    *(unsigned long long*)(ast + ((ub + 8) ^ sw)) = pack4(v1);
}

// 16-step MFMA chain (K=512): A=weight frags, B=activation panel rows (1024 B)
__device__ __forceinline__ f32x4 chain16(const char* wf, const char* ast,
                                         int lane, int n, int kg, f32x4 acc) {
    const int sw = (n & 7) << 4;
    #pragma unroll
    for (int kt = 0; kt < 16; ++kt) {
        short8 a = *(const short8*)(wf + kt * 1024 + lane * 16);
        short8 b = *(const short8*)(ast + ((n * 1024 + ((kt * 32 + kg * 8) << 1)) ^ sw));
        acc = __builtin_amdgcn_mfma_f32_16x16x32_bf16(a, b, acc, 0, 0, 0);
    }
    return acc;
}
// 8-step chain (K=256): x tile rows of 512 B
__device__ __forceinline__ f32x4 chain8(const char* wf, const char* ast,
                                        int lane, int n, int kg, f32x4 acc) {
    const int sw = (n & 7) << 4;
    #pragma unroll
    for (int kt = 0; kt < 8; ++kt) {
        short8 a = *(const short8*)(wf + kt * 1024 + lane * 16);
        short8 b = *(const short8*)(ast + ((n * 512 + ((kt * 32 + kg * 8) << 1)) ^ sw));
        acc = __builtin_amdgcn_mfma_f32_16x16x32_bf16(a, b, acc, 0, 0, 0);
    }
    return acc;
}

__global__ __launch_bounds__(NTH, 1) void scagru_x8(
    const float* __restrict__ input, const float* __restrict__ state,
    const float* __restrict__ W_zh, const float* __restrict__ W_zx, const float* __restrict__ b_z,
    const float* __restrict__ W_rh, const float* __restrict__ W_rx, const float* __restrict__ b_r,
    const float* __restrict__ W_hh, const float* __restrict__ W_hx, const float* __restrict__ b_h,
    const float* __restrict__ W_ch, const float* __restrict__ b_c,
    float* __restrict__ out,
    unsigned short* __restrict__ hP, unsigned short* __restrict__ hrP,
    int* __restrict__ claim, int* __restrict__ ready,
    int* __restrict__ hfl, int* __restrict__ hrfl)
{
    const int tid  = threadIdx.x;
    const int lane = tid & 63;
    const int wv   = tid >> 6;                 // 0..7
    const int n    = lane & 15;                // batch row within tile (C col)
    const int kg   = lane >> 4;
    const int m0   = kg * 4;                   // hidden-col quad (C rows)

    __shared__ __align__(16) char smem[SMEM_SZ];
    __shared__ int role_s;
    char*  ast   = smem;
    float* cbase = (float*)(smem + OF_CB);

    // ---- claim XCD-local role; zero own flags; arrive at MALL rendezvous ----
    if (tid == 0) {
        unsigned xcd;
        asm volatile("s_getreg_b32 %0, hwreg(20, 0, 4)" : "=s"(xcd));   // HW_REG_XCC_ID
        xcd &= 7;
        int rank = __hip_atomic_fetch_add(&claim[xcd], 1, __ATOMIC_RELAXED, __HIP_MEMORY_SCOPE_AGENT);
        int role = (rank < NCG) ? (int)xcd * NCG + rank : -1;
        role_s = role;
        if (role >= 0) {
            hfl[role] = 0; hrfl[role] = 0;                       // plain -> local L2
            asm volatile("s_waitcnt vmcnt(0)" ::: "memory");      // zeros in L2 first
        }
        __hip_atomic_fetch_add(ready, 1, __ATOMIC_RELAXED, __HIP_MEMORY_SCOPE_AGENT);
    }
    __syncthreads();
    const int role = role_s;
    if (role < 0) return;
    const int rs = role >> 5, cg = role & 31;
    const int c0 = cg * NC, r0 = rs * RR;

    unsigned short* hPrs  = hP  + (size_t)rs * RR * H_;
    unsigned short* hrPrs = hrP + (size_t)rs * RR * H_;
    volatile int* hfl_rs  = (volatile int*)(hfl  + rs * NCG);
    volatile int* hrfl_rs = (volatile int*)(hrfl + rs * NCG);

    // ---- one-time: 6 weight slices -> MFMA A-frags (72 wave-tasks) ----
    for (int task = wv; task < 72; task += 8) {
        const float* W; char* dst; int kt;
        if      (task < 16) { W = W_zh; dst = smem + OF_WZH; kt = task; }
        else if (task < 32) { W = W_rh; dst = smem + OF_WRH; kt = task - 16; }
        else if (task < 48) { W = W_hh; dst = smem + OF_WHH; kt = task - 32; }
        else if (task < 56) { W = W_zx; dst = smem + OF_WZX; kt = task - 48; }
        else if (task < 64) { W = W_rx; dst = smem + OF_WRX; kt = task - 56; }
        else                { W = W_hx; dst = smem + OF_WHX; kt = task - 64; }
        short8 a;
        #pragma unroll
        for (int j = 0; j < 8; ++j)
            a[j] = (short)f2bf(W[(size_t)(kt * 32 + kg * 8 + j) * H_ + c0 + n]);
        *(short8*)(dst + kt * 1024 + lane * 16) = a;
    }

    // ---- one-time: context base relu(state@W_ch + b_c) for our 16x16 block ----
    if (tid < 256) {
        const int r = tid >> 4, cl = tid & 15;
        const float* srow = state + (size_t)(r0 + r) * H_;
        float acc = 0.f;
        #pragma unroll 8
        for (int k = 0; k < H_; ++k)
            acc = fmaf(srow[k], W_ch[(size_t)k * H_ + c0 + cl], acc);
        cbase[r * 17 + cl] = fmaxf(acc + b_c[c0 + cl], 0.f);
    }

    // ---- stage x(t=0) ----
    stage_x(ast, input + (size_t)r0 * I_, tid);
    __syncthreads();

    // ---- per-wave persistent registers ----
    f32x4 cz = {0,0,0,0}, cr = {0,0,0,0}, ch = {0,0,0,0};
    f32x4 xz = {0,0,0,0}, xr = {0,0,0,0}, xh = {0,0,0,0};
    f32x4 hp = {0,0,0,0}, zfrag = {0,0,0,0};
    if (wv == 0) {
        #pragma unroll
        for (int q = 0; q < 4; ++q) {
            float b = cbase[n * 17 + m0 + q];
            cz[q] = b + b_z[c0 + m0 + q];
            ch[q] = b + b_h[c0 + m0 + q];
        }
        xz = chain8(smem + OF_WZX, ast, lane, n, kg, cz);
        xh = chain8(smem + OF_WHX, ast, lane, n, kg, ch);
        hp = *(const f32x4*)(state + (size_t)(r0 + n) * H_ + c0 + m0);
    } else if (wv == 1) {
        #pragma unroll
        for (int q = 0; q < 4; ++q)
            cr[q] = cbase[n * 17 + m0 + q] + b_r[c0 + m0 + q];
        xr = chain8(smem + OF_WRX, ast, lane, n, kg, cr);
    }

    // ---- rendezvous: all 256 wgs claimed + zeroed (capped MALL poll) ----
    if (tid == 0) {
        int it = 0;
        while (__hip_atomic_load(ready, __ATOMIC_RELAXED, __HIP_MEMORY_SCOPE_AGENT) < NWG) {
            if (++it > 4000000) break;
            __builtin_amdgcn_s_sleep(8);
        }
    }
    __syncthreads();

    // ---- publish h_0 (plain stores -> local L2) ----
    if (wv == 0) {
        float v[4] = {hp[0], hp[1], hp[2], hp[3]};
        *(unsigned long long*)(hPrs + (size_t)n * H_ + c0 + m0) = pack4(v);
    }
    __syncthreads();
    if (tid == 0) *(volatile int*)&hfl[role] = 1;

    bool dead = false;

    for (int t = 0; t < T_; ++t) {
        // ================= phase A: z & r =================
        if (tid < NCG) wait_local(&hfl_rs[tid], t + 1, dead);
        __syncthreads();
        stage_panel(ast, hPrs, tid);
        __syncthreads();

        if (wv == 0) {
            f32x4 acc = chain16(smem + OF_WZH, ast, lane, n, kg, xz);
            #pragma unroll
            for (int q = 0; q < 4; ++q) zfrag[q] = sigmoidf_(acc[q]);
        } else if (wv == 1) {
            f32x4 acc = chain16(smem + OF_WRH, ast, lane, n, kg, xr);
            const int sw = (n & 7) << 4;
            float hv[4], v[4];
            unpack4(*(const unsigned long long*)(ast + ((n * 1024 + ((c0 + m0) << 1)) ^ sw)), hv);
            #pragma unroll
            for (int q = 0; q < 4; ++q) v[q] = sigmoidf_(acc[q]) * hv[q];
            *(unsigned long long*)(hrPrs + (size_t)n * H_ + c0 + m0) = pack4(v);
        }
        __syncthreads();                                    // drains hr stores
        if (tid == 0) *(volatile int*)&hrfl_rs[cg] = t + 1;

        // ================= phase B: h-candidate + update =================
        if (tid < NCG) wait_local(&hrfl_rs[tid], t + 1, dead);
        __syncthreads();
        stage_panel(ast, hrPrs, tid);
        __syncthreads();

        if (wv == 0) {
            f32x4 acc = chain16(smem + OF_WHH, ast, lane, n, kg, xh);
            float hn[4];
            #pragma unroll
            for (int q = 0; q < 4; ++q) {
                float hc = tanhf(acc[q]);
                hn[q] = (1.f - zfrag[q]) * hp[q] + zfrag[q] * hc;
                hp[q] = hn[q];
            }
            *(unsigned long long*)(hPrs + (size_t)n * H_ + c0 + m0) = pack4(hn);
            if (t == T_ - 1)
                *(float4*)(out + (size_t)(r0 + n) * H_ + c0 + m0) =
                    make_float4(hn[0], hn[1], hn[2], hn[3]);
        }
        __syncthreads();                                    // drains h stores
        if (tid == 0) *(volatile int*)&hfl_rs[cg] = t + 2;

        // ---- x-projection for t+1 (local; hidden behind others' phases) ----
        if (t + 1 < T_) {
            stage_x(ast, input + ((size_t)(t + 1) * B_ + r0) * I_, tid);
            __syncthreads();
            if (wv == 0) {
                xz = chain8(smem + OF_WZX, ast, lane, n, kg, cz);
                xh = chain8(smem + OF_WHX, ast, lane, n, kg, ch);
            } else if (wv == 1) {
                xr = chain8(smem + OF_WRX, ast, lane, n, kg, cr);
            }
            // next loop's post-poll __syncthreads orders these reads vs restage
        }
    }
}

extern "C" void kernel_launch(void* const* d_in, const int* in_sizes, int n_in,
                              void* d_out, int out_size, void* d_ws, size_t ws_size,
                              hipStream_t stream)
{
    const float* input = (const float*)d_in[0];
    const float* state = (const float*)d_in[1];
    const float* W_zh  = (const float*)d_in[2];
    const float* W_zx  = (const float*)d_in[3];
    const float* b_z   = (const float*)d_in[4];
    const float* W_rh  = (const float*)d_in[5];
    const float* W_rx  = (const float*)d_in[6];
    const float* b_r   = (const float*)d_in[7];
    const float* W_hh  = (const float*)d_in[8];
    const float* W_hx  = (const float*)d_in[9];
    const float* b_h   = (const float*)d_in[10];
    const float* W_ch  = (const float*)d_in[11];
    const float* b_c   = (const float*)d_in[12];

    float* out = (float*)d_out;
    char*  ws  = (char*)d_ws;

    unsigned short* hP  = (unsigned short*)(ws);              // [8][16][512] bf16 = 128 KB
    unsigned short* hrP = (unsigned short*)(ws + 131072);     // [8][16][512] bf16 = 128 KB
    char* ctrl = ws + 262144;
    int* claim = (int*)(ctrl);                                // [8]
    int* ready = (int*)(ctrl + 128);                          // [1]
    int* hfl   = (int*)(ctrl + 512);                          // [8][32]
    int* hrfl  = (int*)(ctrl + 1536);                         // [8][32]

    hipMemsetAsync(ctrl, 0, 256, stream);                     // claim + ready only

    scagru_x8<<<dim3(NWG), dim3(NTH), 0, stream>>>(
        input, state,
        W_zh, W_zx, b_z, W_rh, W_rx, b_r, W_hh, W_hx, b_h, W_ch, b_c,
        out, hP, hrP, claim, ready, hfl, hrfl);
}